// Round 16
// baseline (6154.178 us; speedup 1.0000x reference)
//
#include <hip/hip_runtime.h>
#include <cstdint>
#include <cstddef>

#define HID 64

typedef short bf16x8 __attribute__((ext_vector_type(8)));
typedef float f32x4 __attribute__((ext_vector_type(4)));
typedef float f32x2 __attribute__((ext_vector_type(2)));
typedef unsigned u32x4 __attribute__((ext_vector_type(4)));

__device__ __forceinline__ f32x2 c2(float v) { f32x2 r = {v, v}; return r; }

// Packed exact-erf GELU (A&S 7.1.26, max |erf err| ~1.5e-7) on two elements.
__device__ __forceinline__ f32x2 fast_gelu2(f32x2 z) {
    const f32x2 u = z * 0.70710678118654752f;
    const f32x2 a = __builtin_elementwise_abs(u);
    const f32x2 d = __builtin_elementwise_fma(c2(0.3275911f), a, c2(1.0f));
    f32x2 t;
    t.x = __builtin_amdgcn_rcpf(d.x);
    t.y = __builtin_amdgcn_rcpf(d.y);
    const f32x2 s = u * 1.20112240878645f;      // sqrt(log2 e)
    f32x2 e;
    e.x = __builtin_amdgcn_exp2f(-(s.x * s.x)); // exp(-u^2)
    e.y = __builtin_amdgcn_exp2f(-(s.y * s.y));
    f32x2 p = c2(1.061405429f);
    p = __builtin_elementwise_fma(p, t, c2(-1.453152027f));
    p = __builtin_elementwise_fma(p, t, c2( 1.421413741f));
    p = __builtin_elementwise_fma(p, t, c2(-0.284496736f));
    p = __builtin_elementwise_fma(p, t, c2( 0.254829592f));
    p = p * t;
    f32x2 er = __builtin_elementwise_fma(-p, e, c2(1.0f));
    er = __builtin_elementwise_copysign(er, u);
    const f32x2 zh = z * 0.5f;
    return __builtin_elementwise_fma(zh, er, zh);
}

__device__ __forceinline__ ushort bf16_hi(float f) {
    return (ushort)(__float_as_uint(f) >> 16);
}
__device__ __forceinline__ float bf16_f(ushort u) {
    return __uint_as_float(((unsigned)u) << 16);
}

// Pack top halves of two f32 bit-patterns into one u32: {lo16=a>>16, hi16=b>>16}.
#define PKHI(b_, a_) __builtin_amdgcn_perm((b_), (a_), 0x07060302u)

__device__ __forceinline__ bf16x8 mk8(unsigned a, unsigned b, unsigned c, unsigned d) {
    union { u32x4 u; bf16x8 v; } w;
    w.u = (u32x4){a, b, c, d};
    return w.v;
}

#define MF(A_, B_, C_) __builtin_amdgcn_mfma_f32_16x16x32_bf16((A_), (B_), (C_), 0, 0, 0)

// Load W^T A-fragment for c-tile t, K-half hf, under the CUSTOM slot->k map
// k(q,e,hf) = 32*hf + 16*(e>>2) + 4q + (e&3)   (bijection per MFMA call).
// With this map, a lane's step-t D elements (tiles 2hf,2hf+1) ARE its step-t+1
// B-fragment for half hf -- no cross-lane exchange needed, ever.
#define LDW(VH, VL, t, hf) { \
    _Pragma("unroll") \
    for (int e = 0; e < 8; ++e) { \
        const int k = 32 * (hf) + 16 * (e >> 2) + 4 * q + (e & 3); \
        const float wf = W_s[k * HID + 16 * (t) + rr]; \
        const ushort hb = bf16_hi(wf); \
        VH[e] = (short)hb; \
        VL[e] = (short)bf16_hi(wf - bf16_f(hb)); \
    } }

// One fully in-register step. acc[t] = ci[t] + W^T_t (hi+lo) x h (hi+lo),
// dropping lo*lo. GELU -> split-bf16 -> repack directly into next B-frags.
#define STEP(XB) { \
    const f32x4 xb4 = {(XB), (XB), (XB), (XB)}; \
    f32x4 a0 = __builtin_elementwise_fma(xb4, wn0, cv0); \
    f32x4 a1 = __builtin_elementwise_fma(xb4, wn1, cv1); \
    f32x4 a2 = __builtin_elementwise_fma(xb4, wn2, cv2); \
    f32x4 a3 = __builtin_elementwise_fma(xb4, wn3, cv3); \
    a0 = MF(WH00, BH0, a0); a1 = MF(WH10, BH0, a1); a2 = MF(WH20, BH0, a2); a3 = MF(WH30, BH0, a3); \
    a0 = MF(WH01, BH1, a0); a1 = MF(WH11, BH1, a1); a2 = MF(WH21, BH1, a2); a3 = MF(WH31, BH1, a3); \
    a0 = MF(WH00, BL0, a0); a1 = MF(WH10, BL0, a1); a2 = MF(WH20, BL0, a2); a3 = MF(WH30, BL0, a3); \
    a0 = MF(WH01, BL1, a0); a1 = MF(WH11, BL1, a1); a2 = MF(WH21, BL1, a2); a3 = MF(WH31, BL1, a3); \
    a0 = MF(WL00, BH0, a0); a1 = MF(WL10, BH0, a1); a2 = MF(WL20, BH0, a2); a3 = MF(WL30, BH0, a3); \
    a0 = MF(WL01, BH1, a0); a1 = MF(WL11, BH1, a1); a2 = MF(WL21, BH1, a2); a3 = MF(WL31, BH1, a3); \
    f32x2 z; \
    z.x = a0[0]; z.y = a0[1]; const f32x2 g0a = fast_gelu2(z); \
    z.x = a0[2]; z.y = a0[3]; const f32x2 g0b = fast_gelu2(z); \
    z.x = a1[0]; z.y = a1[1]; const f32x2 g1a = fast_gelu2(z); \
    z.x = a1[2]; z.y = a1[3]; const f32x2 g1b = fast_gelu2(z); \
    z.x = a2[0]; z.y = a2[1]; const f32x2 g2a = fast_gelu2(z); \
    z.x = a2[2]; z.y = a2[3]; const f32x2 g2b = fast_gelu2(z); \
    z.x = a3[0]; z.y = a3[1]; const f32x2 g3a = fast_gelu2(z); \
    z.x = a3[2]; z.y = a3[3]; const f32x2 g3b = fast_gelu2(z); \
    const unsigned h0a = PKHI(__float_as_uint(g0a.y), __float_as_uint(g0a.x)); \
    const unsigned h0b = PKHI(__float_as_uint(g0b.y), __float_as_uint(g0b.x)); \
    const unsigned h1a = PKHI(__float_as_uint(g1a.y), __float_as_uint(g1a.x)); \
    const unsigned h1b = PKHI(__float_as_uint(g1b.y), __float_as_uint(g1b.x)); \
    const unsigned h2a = PKHI(__float_as_uint(g2a.y), __float_as_uint(g2a.x)); \
    const unsigned h2b = PKHI(__float_as_uint(g2b.y), __float_as_uint(g2b.x)); \
    const unsigned h3a = PKHI(__float_as_uint(g3a.y), __float_as_uint(g3a.x)); \
    const unsigned h3b = PKHI(__float_as_uint(g3b.y), __float_as_uint(g3b.x)); \
    const f32x2 l0a = g0a - TR2(g0a); const f32x2 l0b = g0b - TR2(g0b); \
    const f32x2 l1a = g1a - TR2(g1a); const f32x2 l1b = g1b - TR2(g1b); \
    const f32x2 l2a = g2a - TR2(g2a); const f32x2 l2b = g2b - TR2(g2b); \
    const f32x2 l3a = g3a - TR2(g3a); const f32x2 l3b = g3b - TR2(g3b); \
    BH0 = mk8(h0a, h0b, h1a, h1b); \
    BH1 = mk8(h2a, h2b, h3a, h3b); \
    BL0 = mk8(PKHI(__float_as_uint(l0a.y), __float_as_uint(l0a.x)), \
              PKHI(__float_as_uint(l0b.y), __float_as_uint(l0b.x)), \
              PKHI(__float_as_uint(l1a.y), __float_as_uint(l1a.x)), \
              PKHI(__float_as_uint(l1b.y), __float_as_uint(l1b.x))); \
    BL1 = mk8(PKHI(__float_as_uint(l2a.y), __float_as_uint(l2a.x)), \
              PKHI(__float_as_uint(l2b.y), __float_as_uint(l2b.x)), \
              PKHI(__float_as_uint(l3a.y), __float_as_uint(l3a.x)), \
              PKHI(__float_as_uint(l3b.y), __float_as_uint(l3b.x))); }

// bf16-truncation of both elements (bitmask), packed.
__device__ __forceinline__ f32x2 TR2(f32x2 v) {
    f32x2 r;
    r.x = __uint_as_float(__float_as_uint(v.x) & 0xffff0000u);
    r.y = __uint_as_float(__float_as_uint(v.y) & 0xffff0000u);
    return r;
}

__global__ __launch_bounds__(64, 1)
void ssm_kernel(const float* __restrict__ x,
                const float* __restrict__ W_in,
                const float* __restrict__ b_in,
                const float* __restrict__ W_s,
                const float* __restrict__ b_s,
                const float* __restrict__ W_out,
                const float* __restrict__ b_out,
                float* __restrict__ out,
                int B, int T) {
    const int lane = threadIdx.x & 63;
    const int q    = lane >> 4;       // k-slot group / D row-quad group
    const int rr   = lane & 15;       // batch row (A's c-row AND D's r-col)
    const int bA   = blockIdx.x * 16;
    if (bA >= B) return;

    // Static W^T fragments (hi+lo split), custom k-map. 64 VGPRs.
    bf16x8 WH00, WH01, WH10, WH11, WH20, WH21, WH30, WH31;
    bf16x8 WL00, WL01, WL10, WL11, WL20, WL21, WL30, WL31;
    LDW(WH00, WL00, 0, 0) LDW(WH01, WL01, 0, 1)
    LDW(WH10, WL10, 1, 0) LDW(WH11, WL11, 1, 1)
    LDW(WH20, WL20, 2, 0) LDW(WH21, WL21, 2, 1)
    LDW(WH30, WL30, 3, 0) LDW(WH31, WL31, 3, 1)
    asm volatile("" : "+v"(WH00), "+v"(WH01), "+v"(WH10), "+v"(WH11),
                      "+v"(WH20), "+v"(WH21), "+v"(WH30), "+v"(WH31));
    asm volatile("" : "+v"(WL00), "+v"(WL01), "+v"(WL10), "+v"(WL11),
                      "+v"(WL20), "+v"(WL21), "+v"(WL30), "+v"(WL31));

    // Per-tile input-projection constants: el e of tile t is c = 16t + 4q + e.
    f32x4 wn0, wn1, wn2, wn3, cv0, cv1, cv2, cv3;
#pragma unroll
    for (int e = 0; e < 4; ++e) {
        wn0[e] = W_in[ 0 + 4 * q + e];  cv0[e] = b_in[ 0 + 4 * q + e] + b_s[ 0 + 4 * q + e];
        wn1[e] = W_in[16 + 4 * q + e];  cv1[e] = b_in[16 + 4 * q + e] + b_s[16 + 4 * q + e];
        wn2[e] = W_in[32 + 4 * q + e];  cv2[e] = b_in[32 + 4 * q + e] + b_s[32 + 4 * q + e];
        wn3[e] = W_in[48 + 4 * q + e];  cv3[e] = b_in[48 + 4 * q + e] + b_s[48 + 4 * q + e];
    }

    // h state (B-fragments), fully in registers. h0 = 0.
    bf16x8 BH0 = mk8(0, 0, 0, 0), BH1 = mk8(0, 0, 0, 0);
    bf16x8 BL0 = mk8(0, 0, 0, 0), BL1 = mk8(0, 0, 0, 0);

    // This lane's x row (4 steps per f32x4 load; row base is 16B-aligned).
    const float* const xp = x + (size_t)(bA + rr) * (size_t)T;
    const int n4 = T >> 2;
    f32x4 xq = *reinterpret_cast<const f32x4*>(xp);

#pragma unroll 1
    for (int tc = 0; tc < n4; ++tc) {
        const int nx = (tc + 1 < n4) ? (tc + 1) : tc;   // clamped prefetch
        const f32x4 xn = *reinterpret_cast<const f32x4*>(xp + 4 * nx);
        STEP(xq[0])
        STEP(xq[1])
        STEP(xq[2])
        STEP(xq[3])
        xq = xn;
    }

    // Epilogue: lane holds h[c = 16t+4q+e][rr] as (BH,BL) el (t&1)*4+e of
    // half t>>1. out[b] = h . W_out + b_out, reduced over the 4 q-lanes.
    float s = 0.f;
#pragma unroll
    for (int t = 0; t < 4; ++t) {
        const bf16x8 bh = (t < 2) ? BH0 : BH1;
        const bf16x8 bl = (t < 2) ? BL0 : BL1;
#pragma unroll
        for (int e = 0; e < 4; ++e) {
            const int i = (t & 1) * 4 + e;
            const float hv = bf16_f((ushort)bh[i]) + bf16_f((ushort)bl[i]);
            s = __builtin_fmaf(hv, W_out[16 * t + 4 * q + e], s);
        }
    }
    s += __shfl_xor(s, 16, 64);
    s += __shfl_xor(s, 32, 64);
    if (lane < 16) out[bA + rr] = s + b_out[0];
}

extern "C" void kernel_launch(void* const* d_in, const int* in_sizes, int n_in,
                              void* d_out, int out_size, void* d_ws, size_t ws_size,
                              hipStream_t stream) {
    const float* x     = (const float*)d_in[0];
    const float* W_in  = (const float*)d_in[1];
    const float* b_in  = (const float*)d_in[2];
    const float* W_s   = (const float*)d_in[3];
    const float* b_s   = (const float*)d_in[4];
    const float* W_out = (const float*)d_in[5];
    const float* b_out = (const float*)d_in[6];
    float* out = (float*)d_out;

    const int B = out_size;                 // [B,1] output
    const int T = in_sizes[0] / B;          // x is [B,T,1]

    const int blocks = B / 16;              // 256 for B=4096 -> 1 block/CU
    ssm_kernel<<<blocks, 64, 0, stream>>>(
        x, W_in, b_in, W_s, b_s, W_out, b_out, out, B, T);
}